// Round 12
// baseline (164.356 us; speedup 1.0000x reference)
//
#include <hip/hip_runtime.h>
#include <hip/hip_fp16.h>
#include <math.h>

#define N_NODES 50000
#define IN_F 256
#define OUT_F 64
#define NBUCK 512   // buckets of 98 rows -> reduce grid = exactly 2 blocks/CU
#define BROWS 98
#define CHUNK 3136  // edges per bin block -> G = 511 ~= 2 blocks per CU
#define NI4   (CHUNK / 4)
#define CAPB 3584   // bucket capacity: mean 3136 + 8 sigma (sigma=56)

typedef unsigned int uint;
typedef __attribute__((ext_vector_type(8))) short short8v;
typedef __attribute__((ext_vector_type(4))) short short4v;
typedef __attribute__((ext_vector_type(4))) float f32x4;

// ---------------------------------------------------------------------------
// 4-kernel pipeline (round-12 = round-11 + bin in-LDS bucket sort so the
// global scatter is run-coalesced, and 2 co-resident bin blocks/CU):
//   wprep:  W fp32 -> bf16 hi/lo split, transposed [col][k]; zeroes gcnt.
//   gemm:   support = feat @ W via MFMA bf16x2 3-term split, stored FP16.
//   bin:    per block: stage 3136 edges + 512-bucket hist -> scan -> rank-
//           scatter into bucket-SORTED LDS buffer (bucket id in 9 spare
//           bits) -> one global base-claim per (block,bucket) -> linear
//           global write addr = off[bucket]+i (contiguous within runs).
//   reduce: one block per 98-row bucket, 1024 thr, 58.8 KB LDS -> 2/CU,
//           LDS stage + hist/scan/sort (int atomics), half-wave-per-edge
//           register reduce, fused tanh (round-11 verbatim).
// ---------------------------------------------------------------------------

__device__ __forceinline__ short bf16_trunc(float f) {
    return (short)(__float_as_uint(f) >> 16);
}
__device__ __forceinline__ float bf16_tof(short s) {
    return __uint_as_float(((uint)(unsigned short)s) << 16);
}
__device__ __forceinline__ short bf16_rne(float f) {
    uint u = __float_as_uint(f);
    uint r = u + 0x7FFF + ((u >> 16) & 1);
    return (short)(r >> 16);
}

// ---- W prep: transpose + bf16x2 split; zero bucket counters ----
__global__ __launch_bounds__(256) void wprep_kernel(const float* __restrict__ W,
                                                    short* __restrict__ Whi,
                                                    short* __restrict__ Wlo,
                                                    int* __restrict__ gcnt) {
    const int t = threadIdx.x;
    const int k0 = blockIdx.x * 32;
    if (blockIdx.x == 0) {
        for (int i = t; i < NBUCK; i += 256) gcnt[i] = 0;
    }

    __shared__ float buf[32][65];
    for (int i = t; i < 32 * 64; i += 256) {
        int kk = i >> 6, c = i & 63;
        buf[kk][c] = W[(k0 + kk) * 64 + c];   // coalesced
    }
    __syncthreads();
    {
        int c = t & 63, g = t >> 6;  // 64 cols x 4 octets of k
        short8v vh, vl;
        for (int j = 0; j < 8; ++j) {
            float f = buf[g * 8 + j][c];
            short h = bf16_trunc(f);
            vh[j] = h;
            vl[j] = bf16_rne(f - bf16_tof(h));
        }
        *(short8v*)&Whi[c * IN_F + k0 + g * 8] = vh;
        *(short8v*)&Wlo[c * IN_F + k0 + g * 8] = vl;
    }
}

// ---- MFMA bf16x2 projection: support(FP16) = feat @ W ----
// block: 256 thr (4 waves), 128 rows x 64 cols; wave: 32 rows (M_rep=2, N_rep=4)
__global__ __launch_bounds__(256) void gemm_kernel(const float* __restrict__ feat,
                                                   const short* __restrict__ Whi,
                                                   const short* __restrict__ Wlo,
                                                   __half* __restrict__ sup) {
    __shared__ short lds[15360];          // 30 KB
    short* As_hi = lds;                   // 128 x 40 halves (80B stride)
    short* As_lo = lds + 5120;
    short* Bs_hi = lds + 10240;           // 64 x 40 halves
    short* Bs_lo = lds + 12800;

    const int t = threadIdx.x;
    const int row0 = blockIdx.x * 128;
    const int l = t & 63;
    const int lr = l & 15;
    const int lk = (l >> 4) * 8;
    const int wrow = (t >> 6) * 32;

    // A staging ids: 2 threads per row, 16 floats each
    const int ar = t >> 1, aq = t & 1;
    int gr = row0 + ar; if (gr >= N_NODES) gr = N_NODES - 1;
    const float4* asrc = (const float4*)(feat + (size_t)gr * IN_F);
    // B staging ids: 4 threads per col, 8 k each
    const int bc = t >> 2, bp = t & 3;

    f32x4 acc[2][4];
#pragma unroll
    for (int m = 0; m < 2; ++m)
#pragma unroll
        for (int nn = 0; nn < 4; ++nn) acc[m][nn] = (f32x4)(0.f);

    for (int ch = 0; ch < 8; ++ch) {
        // prefetch chunk into regs
        float4 av[4];
#pragma unroll
        for (int i = 0; i < 4; ++i) av[i] = asrc[ch * 8 + aq * 4 + i];
        short8v bh = *(const short8v*)(Whi + bc * IN_F + ch * 32 + bp * 8);
        short8v bl = *(const short8v*)(Wlo + bc * IN_F + ch * 32 + bp * 8);

        __syncthreads();   // prior chunk's readers done
#pragma unroll
        for (int i = 0; i < 4; ++i) {
            float fx[4] = {av[i].x, av[i].y, av[i].z, av[i].w};
            short4v h4, l4;
#pragma unroll
            for (int j = 0; j < 4; ++j) {
                short h = bf16_trunc(fx[j]);
                h4[j] = h;
                l4[j] = bf16_rne(fx[j] - bf16_tof(h));
            }
            *(short4v*)&As_hi[ar * 40 + aq * 16 + i * 4] = h4;
            *(short4v*)&As_lo[ar * 40 + aq * 16 + i * 4] = l4;
        }
        *(short8v*)&Bs_hi[bc * 40 + bp * 8] = bh;
        *(short8v*)&Bs_lo[bc * 40 + bp * 8] = bl;
        __syncthreads();

        short8v ah[2], al[2], wh[4], wl[4];
#pragma unroll
        for (int m = 0; m < 2; ++m) {
            ah[m] = *(short8v*)&As_hi[(wrow + m * 16 + lr) * 40 + lk];
            al[m] = *(short8v*)&As_lo[(wrow + m * 16 + lr) * 40 + lk];
        }
#pragma unroll
        for (int nn = 0; nn < 4; ++nn) {
            wh[nn] = *(short8v*)&Bs_hi[(nn * 16 + lr) * 40 + lk];
            wl[nn] = *(short8v*)&Bs_lo[(nn * 16 + lr) * 40 + lk];
        }
#pragma unroll
        for (int m = 0; m < 2; ++m)
#pragma unroll
            for (int nn = 0; nn < 4; ++nn) {
                acc[m][nn] = __builtin_amdgcn_mfma_f32_16x16x32_bf16(ah[m], wh[nn], acc[m][nn], 0, 0, 0);
                acc[m][nn] = __builtin_amdgcn_mfma_f32_16x16x32_bf16(ah[m], wl[nn], acc[m][nn], 0, 0, 0);
                acc[m][nn] = __builtin_amdgcn_mfma_f32_16x16x32_bf16(al[m], wh[nn], acc[m][nn], 0, 0, 0);
            }
    }

    // epilogue: transpose via LDS (overlays staging buffers), coalesced store
    __syncthreads();
    short* sup_s = lds;  // 128 x 64 halves = 16 KB
#pragma unroll
    for (int m = 0; m < 2; ++m) {
        int rr = wrow + m * 16 + (l >> 4) * 4;
#pragma unroll
        for (int nn = 0; nn < 4; ++nn) {
            int cc = nn * 16 + lr;
#pragma unroll
            for (int j = 0; j < 4; ++j) {
                __half h = __float2half(acc[m][nn][j]);
                sup_s[(rr + j) * 64 + cc] = *(short*)&h;
            }
        }
    }
    __syncthreads();
    {
        int r = t >> 1, sg = (t & 1) * 32;
        int grow = row0 + r;
        if (grow < N_NODES) {
            const uint4* s4 = (const uint4*)&sup_s[r * 64 + sg];
            uint4* d4 = (uint4*)(sup + (size_t)grow * OUT_F + sg);
            d4[0] = s4[0];
            d4[1] = s4[1];
            d4[2] = s4[2];
            d4[3] = s4[3];
        }
    }
}

// ---- bin: stage + hist + scan + LDS bucket-sort + run-coalesced scatter ----
__global__ __launch_bounds__(1024) void bin_kernel(const int* __restrict__ erow,
                                                   const int* __restrict__ ecol,
                                                   const float* __restrict__ ew,
                                                   int* __restrict__ gcnt,
                                                   int2* __restrict__ ecw, int E) {
    __shared__ uint  pkst[CHUNK];   // (row<<16)|col          12.5 KB
    __shared__ float wst[CHUNK];    // edge weight            12.5 KB
    __shared__ uint  spk[CHUNK];    // sorted (b9|lr7|col16)  12.5 KB
    __shared__ float sw[CHUNK];     // sorted weight          12.5 KB
    __shared__ int h[NBUCK];        // per-bucket count        2 KB
    __shared__ int sc[NBUCK];       // inclusive scan          2 KB
    __shared__ int cur[NBUCK];      // rank cursor             2 KB
    __shared__ int off[NBUCK];      // global base - local start  2 KB
    const int t = threadIdx.x;
    const int base = blockIdx.x * CHUNK;
    const int lim = min(CHUNK, E - base);

    for (int i = t; i < NBUCK; i += 1024) h[i] = 0;
    __syncthreads();

    // phase 1: stage + 512-bucket histogram (bucket = row/98, magic-mul)
    for (int i4 = t; i4 < NI4; i4 += 1024) {
        const int e4 = base + 4 * i4;
        if (e4 + 3 < E) {
            int4   r4 = *(const int4*)(erow + e4);
            int4   c4 = *(const int4*)(ecol + e4);
            float4 w4 = *(const float4*)(ew + e4);
            pkst[4 * i4 + 0] = ((uint)r4.x << 16) | (uint)c4.x;
            pkst[4 * i4 + 1] = ((uint)r4.y << 16) | (uint)c4.y;
            pkst[4 * i4 + 2] = ((uint)r4.z << 16) | (uint)c4.z;
            pkst[4 * i4 + 3] = ((uint)r4.w << 16) | (uint)c4.w;
            *(float4*)(wst + 4 * i4) = w4;
            atomicAdd(&h[(uint)r4.x / BROWS], 1);
            atomicAdd(&h[(uint)r4.y / BROWS], 1);
            atomicAdd(&h[(uint)r4.z / BROWS], 1);
            atomicAdd(&h[(uint)r4.w / BROWS], 1);
        } else {
            for (int k = 0; k < 4; ++k) {
                int e = e4 + k;
                if (e < E) {
                    int row = erow[e];
                    pkst[4 * i4 + k] = ((uint)row << 16) | (uint)ecol[e];
                    wst[4 * i4 + k] = ew[e];
                    atomicAdd(&h[(uint)row / BROWS], 1);
                }
            }
        }
    }
    __syncthreads();

    // phase 2: 512-entry inclusive scan
    if (t < NBUCK) sc[t] = h[t];
    __syncthreads();
    for (int offd = 1; offd < NBUCK; offd <<= 1) {
        int u = (t < NBUCK && t >= offd) ? sc[t - offd] : 0;
        __syncthreads();
        if (t < NBUCK) sc[t] += u;
        __syncthreads();
    }
    // phase 3: rank cursors + global base claim per non-empty bucket
    if (t < NBUCK) {
        int start = sc[t] - h[t];
        cur[t] = start;
        int c = h[t];
        if (c > 0) off[t] = atomicAdd(&gcnt[t], c) - start;
    }
    __syncthreads();

    // phase 4: rank-scatter into bucket-sorted LDS (9-bit bucket id kept)
    for (int i = t; i < lim; i += 1024) {
        uint pk = pkst[i];
        uint row = pk >> 16;
        uint b   = row / BROWS;                // magic-mul
        uint lr  = row - b * BROWS;            // local row 0..97
        int pos = atomicAdd(&cur[b], 1);
        spk[pos] = (b << 23) | (lr << 16) | (pk & 0xFFFF);
        sw[pos]  = wst[i];
    }
    __syncthreads();

    // phase 5: run-coalesced global write (consecutive i in a bucket run
    // map to consecutive global addresses)
    for (int i = t; i < lim; i += 1024) {
        uint pk = spk[i];
        uint b  = pk >> 23;
        int  wp = off[b] + i;                  // position within bucket region
        if (wp < CAPB)
            ecw[(size_t)b * CAPB + wp] =
                make_int2((int)(pk & 0x7FFFFF), __float_as_int(sw[i]));
    }
}

// ---- bucket reduce: LDS sort + register accumulate, 512 blocks (2/CU) ----
__global__ __launch_bounds__(1024) void reduce_kernel(const __half* __restrict__ sup,
                                                      const int* __restrict__ gcnt,
                                                      const int2* __restrict__ ecw,
                                                      const int* __restrict__ active,
                                                      float* __restrict__ out) {
    __shared__ int2 stA[CAPB];   // raw bucket edges      28.7 KB
    __shared__ int2 stB[CAPB];   // row-sorted edges      28.7 KB
    __shared__ int h[128];
    __shared__ int sc[128];
    __shared__ int cur[128];
    const int t = threadIdx.x;
    const int b = blockIdx.x;

    int n = gcnt[b]; if (n > CAPB) n = CAPB;
    const int2* eptr = ecw + (size_t)b * CAPB;

    if (t < 128) h[t] = 0;
    __syncthreads();

    // stage + 98-row histogram (native ds_add_u32)
    for (int i = t; i < n; i += 1024) {
        int2 d = eptr[i];
        stA[i] = d;
        atomicAdd(&h[(d.x >> 16) & 127], 1);
    }
    __syncthreads();

    // 128-entry inclusive scan (entries >= BROWS are zero)
    if (t < 128) sc[t] = h[t];
    __syncthreads();
    for (int off = 1; off < 128; off <<= 1) {
        int u = (t < 128 && t >= off) ? sc[t - off] : 0;
        __syncthreads();
        if (t < 128) sc[t] += u;
        __syncthreads();
    }
    if (t < 128) cur[t] = sc[t] - h[t];
    __syncthreads();

    // scatter to row-sorted order within LDS
    for (int i = t; i < n; i += 1024) {
        int2 d = stA[i];
        int r = (d.x >> 16) & 127;
        int pos = atomicAdd(&cur[r], 1);
        stB[pos] = make_int2(d.x & 0xFFFF, d.y);
    }
    __syncthreads();

    // per-row register reduce: one wave per row, half-wave per edge,
    // each lane gathers a half2 (2 cols) from sup, shfl_xor(32) combine.
    const int wid  = t >> 6;
    const int lane = t & 63;
    const int hl   = lane & 31;
    const bool hi  = lane >= 32;
    const int act  = *active;

    for (int r = wid; r < BROWS; r += 16) {
        int row = b * BROWS + r;
        if (row >= N_NODES) break;   // wave-uniform (tail buckets only)
        const int s = sc[r] - h[r];
        const int e = sc[r];
        float ax = 0.f, ay = 0.f;
        int j = s;
        for (; j + 8 <= e; j += 8) {
#pragma unroll
            for (int q = 0; q < 4; ++q) {
                int2 pa = stB[j + 2 * q];
                int2 pb = stB[j + 2 * q + 1];
                int   col = hi ? pb.x : pa.x;
                float w   = __int_as_float(hi ? pb.y : pa.y);
                const __half2* hp = (const __half2*)(sup + ((size_t)col << 6));
                float2 v = __half22float2(hp[hl]);
                ax += w * v.x;
                ay += w * v.y;
            }
        }
        for (; j + 2 <= e; j += 2) {
            int2 pa = stB[j];
            int2 pb = stB[j + 1];
            int   col = hi ? pb.x : pa.x;
            float w   = __int_as_float(hi ? pb.y : pa.y);
            const __half2* hp = (const __half2*)(sup + ((size_t)col << 6));
            float2 v = __half22float2(hp[hl]);
            ax += w * v.x;
            ay += w * v.y;
        }
        if (j < e) {  // odd tail: hi half contributes zero
            int2 pa = stB[j];
            int   col = pa.x;
            float w   = hi ? 0.f : __int_as_float(pa.y);
            const __half2* hp = (const __half2*)(sup + ((size_t)col << 6));
            float2 v = __half22float2(hp[hl]);
            ax += w * v.x;
            ay += w * v.y;
        }

        ax += __shfl_xor(ax, 32, 64);
        ay += __shfl_xor(ay, 32, 64);

        if (!hi) {
            if (act) { ax = tanhf(ax); ay = tanhf(ay); }
            *(float2*)&out[((size_t)row << 6) + 2 * hl] = make_float2(ax, ay);
        }
    }
}

extern "C" void kernel_launch(void* const* d_in, const int* in_sizes, int n_in,
                              void* d_out, int out_size, void* d_ws, size_t ws_size,
                              hipStream_t stream) {
    const float* feat = (const float*)d_in[0];
    const float* W    = (const float*)d_in[1];
    const int*   erow = (const int*)d_in[2];
    const int*   ecol = (const int*)d_in[3];
    const float* ew   = (const float*)d_in[4];
    const int*   act  = (const int*)d_in[5];
    float* out = (float*)d_out;

    const int E = in_sizes[2];
    const int G = (E + CHUNK - 1) / CHUNK;   // 511 for E = 1.6M

    // workspace carve-up (16B-aligned segments)
    char* ws = (char*)d_ws;
    __half* sup  = (__half*)ws; ws += (size_t)N_NODES * OUT_F * 2;     // 6.4 MB
    int2*   ecw  = (int2*)ws;   ws += (size_t)NBUCK * CAPB * 8;        // 14.7 MB
    int*    gcnt = (int*)ws;    ws += ((size_t)NBUCK * 4 + 15) & ~15;  // 2 KB
    short*  Whi  = (short*)ws;  ws += (size_t)OUT_F * IN_F * 2;        // 32 KB
    short*  Wlo  = (short*)ws;  ws += (size_t)OUT_F * IN_F * 2;        // 32 KB

    wprep_kernel<<<8, 256, 0, stream>>>(W, Whi, Wlo, gcnt);
    gemm_kernel<<<(N_NODES + 127) / 128, 256, 0, stream>>>(feat, Whi, Wlo, sup);
    bin_kernel<<<G, 1024, 0, stream>>>(erow, ecol, ew, gcnt, ecw, E);
    reduce_kernel<<<NBUCK, 1024, 0, stream>>>(sup, gcnt, ecw, act, out);
}

// Round 13
// 161.690 us; speedup vs baseline: 1.0165x; 1.0165x over previous
//
#include <hip/hip_runtime.h>
#include <hip/hip_fp16.h>
#include <math.h>

#define N_NODES 50000
#define IN_F 256
#define OUT_F 64
#define NBUCK 512   // buckets of 98 rows -> reduce grid = exactly 2 blocks/CU
#define BROWS 98
#define CHUNK 6272  // edges per bin block -> G = 256 = one per CU
#define NI4   (CHUNK / 4)
#define CAPB 3584   // bucket capacity: mean 3136 + 8 sigma (sigma=56)

typedef unsigned int uint;
typedef __attribute__((ext_vector_type(8))) short short8v;
typedef __attribute__((ext_vector_type(4))) short short4v;
typedef __attribute__((ext_vector_type(4))) float f32x4;

// ---------------------------------------------------------------------------
// 3-kernel pipeline (round-13 = round-11 minus the wprep kernel):
//   gemm:   support = feat @ W via MFMA bf16x2 3-term split, stored FP16.
//           Each block splits its own W-chunk (fp32->bf16 hi/lo) inline
//           during B-staging (W is 64KB, L2-hot; split is ~32 wave-inst per
//           chunk). Block 0 zeroes gcnt (stream-ordered before bin).
//   bin:    single-pass 512-bucket binning (bucket = row/98 via magic-mul),
//           256 blocks (1/CU), int LDS atomics + one global base-claim per
//           (block,bucket), packed (lrow7|col16, w).   [round-11 verbatim]
//   reduce: one block per 98-row bucket, 1024 thr, 58.8 KB LDS -> 2/CU,
//           512 blocks = full co-residency from t=0. LDS stage + hist/scan/
//           sort (int atomics), half-wave-per-edge register reduce, tanh.
//           [round-11 verbatim]
// ---------------------------------------------------------------------------

__device__ __forceinline__ short bf16_trunc(float f) {
    return (short)(__float_as_uint(f) >> 16);
}
__device__ __forceinline__ float bf16_tof(short s) {
    return __uint_as_float(((uint)(unsigned short)s) << 16);
}
__device__ __forceinline__ short bf16_rne(float f) {
    uint u = __float_as_uint(f);
    uint r = u + 0x7FFF + ((u >> 16) & 1);
    return (short)(r >> 16);
}

// ---- MFMA bf16x2 projection: support(FP16) = feat @ W; zeroes gcnt ----
// block: 256 thr (4 waves), 128 rows x 64 cols; wave: 32 rows (M_rep=2, N_rep=4)
__global__ __launch_bounds__(256) void gemm_kernel(const float* __restrict__ feat,
                                                   const float* __restrict__ W,
                                                   __half* __restrict__ sup,
                                                   int* __restrict__ gcnt) {
    // stream-ordered init of bucket counters (gemm completes before bin runs)
    if (blockIdx.x == 0) {
        for (int i = threadIdx.x; i < NBUCK; i += 256) gcnt[i] = 0;
    }

    __shared__ short lds[15360];          // 30 KB
    short* As_hi = lds;                   // 128 x 40 halves (80B stride)
    short* As_lo = lds + 5120;
    short* Bs_hi = lds + 10240;           // 64 x 40 halves
    short* Bs_lo = lds + 12800;

    const int t = threadIdx.x;
    const int row0 = blockIdx.x * 128;
    const int l = t & 63;
    const int lr = l & 15;
    const int lk = (l >> 4) * 8;
    const int wrow = (t >> 6) * 32;

    // A staging ids: 2 threads per row, 16 floats each
    const int ar = t >> 1, aq = t & 1;
    int gr = row0 + ar; if (gr >= N_NODES) gr = N_NODES - 1;
    const float4* asrc = (const float4*)(feat + (size_t)gr * IN_F);
    // B staging ids: thread t covers k=kk, cols c0..c0+7 of the W chunk
    const int kk = t >> 3, c0 = (t & 7) * 8;
    const float4* wsrc = (const float4*)W;   // W is [256][64] row-major

    f32x4 acc[2][4];
#pragma unroll
    for (int m = 0; m < 2; ++m)
#pragma unroll
        for (int nn = 0; nn < 4; ++nn) acc[m][nn] = (f32x4)(0.f);

    float4 av[4];
#pragma unroll
    for (int i = 0; i < 4; ++i) av[i] = asrc[aq * 4 + i];
    float4 bv0 = wsrc[(kk * 64 + c0) >> 2];
    float4 bv1 = wsrc[((kk * 64 + c0) >> 2) + 1];

    for (int ch = 0; ch < 8; ++ch) {
        {
            // A: split 16 staged floats to bf16 hi/lo
#pragma unroll
            for (int i = 0; i < 4; ++i) {
                float fx[4] = {av[i].x, av[i].y, av[i].z, av[i].w};
                short4v h4, l4;
#pragma unroll
                for (int j = 0; j < 4; ++j) {
                    short h = bf16_trunc(fx[j]);
                    h4[j] = h;
                    l4[j] = bf16_rne(fx[j] - bf16_tof(h));
                }
                *(short4v*)&As_hi[ar * 40 + aq * 16 + i * 4] = h4;
                *(short4v*)&As_lo[ar * 40 + aq * 16 + i * 4] = l4;
            }
            // B: split 8 W floats (row kk, cols c0..c0+7) into [col][k] LDS
            float bf[8] = {bv0.x, bv0.y, bv0.z, bv0.w, bv1.x, bv1.y, bv1.z, bv1.w};
#pragma unroll
            for (int j = 0; j < 8; ++j) {
                short h = bf16_trunc(bf[j]);
                Bs_hi[(c0 + j) * 40 + kk] = h;
                Bs_lo[(c0 + j) * 40 + kk] = bf16_rne(bf[j] - bf16_tof(h));
            }
        }
        __syncthreads();

        if (ch < 7) {
            // prefetch next chunk
#pragma unroll
            for (int i = 0; i < 4; ++i) av[i] = asrc[(ch + 1) * 8 + aq * 4 + i];
            int wb = (((ch + 1) * 32 + kk) * 64 + c0) >> 2;
            bv0 = wsrc[wb];
            bv1 = wsrc[wb + 1];
        }

        short8v ah[2], al[2], wh[4], wl[4];
#pragma unroll
        for (int m = 0; m < 2; ++m) {
            ah[m] = *(short8v*)&As_hi[(wrow + m * 16 + lr) * 40 + lk];
            al[m] = *(short8v*)&As_lo[(wrow + m * 16 + lr) * 40 + lk];
        }
#pragma unroll
        for (int nn = 0; nn < 4; ++nn) {
            wh[nn] = *(short8v*)&Bs_hi[(nn * 16 + lr) * 40 + lk];
            wl[nn] = *(short8v*)&Bs_lo[(nn * 16 + lr) * 40 + lk];
        }
#pragma unroll
        for (int m = 0; m < 2; ++m)
#pragma unroll
            for (int nn = 0; nn < 4; ++nn) {
                acc[m][nn] = __builtin_amdgcn_mfma_f32_16x16x32_bf16(ah[m], wh[nn], acc[m][nn], 0, 0, 0);
                acc[m][nn] = __builtin_amdgcn_mfma_f32_16x16x32_bf16(ah[m], wl[nn], acc[m][nn], 0, 0, 0);
                acc[m][nn] = __builtin_amdgcn_mfma_f32_16x16x32_bf16(al[m], wh[nn], acc[m][nn], 0, 0, 0);
            }
        __syncthreads();
    }

    // epilogue: transpose via LDS (overlays staging buffers), coalesced store
    short* sup_s = lds;  // 128 x 64 halves = 16 KB
#pragma unroll
    for (int m = 0; m < 2; ++m) {
        int rr = wrow + m * 16 + (l >> 4) * 4;
#pragma unroll
        for (int nn = 0; nn < 4; ++nn) {
            int cc = nn * 16 + lr;
#pragma unroll
            for (int j = 0; j < 4; ++j) {
                __half h = __float2half(acc[m][nn][j]);
                sup_s[(rr + j) * 64 + cc] = *(short*)&h;
            }
        }
    }
    __syncthreads();
    {
        int r = t >> 1, sg = (t & 1) * 32;
        int grow = row0 + r;
        if (grow < N_NODES) {
            const uint4* s4 = (const uint4*)&sup_s[r * 64 + sg];
            uint4* d4 = (uint4*)(sup + (size_t)grow * OUT_F + sg);
            d4[0] = s4[0];
            d4[1] = s4[1];
            d4[2] = s4[2];
            d4[3] = s4[3];
        }
    }
}

// ---- single-pass bucket binning (int LDS atomics only), 256 blocks ----
__global__ __launch_bounds__(1024) void bin_kernel(const int* __restrict__ erow,
                                                   const int* __restrict__ ecol,
                                                   const float* __restrict__ ew,
                                                   int* __restrict__ gcnt,
                                                   int2* __restrict__ ecw, int E) {
    __shared__ int   h[NBUCK];      // hist -> absolute cursor   2 KB
    __shared__ uint  pkst[CHUNK];   // (row<<16)|col   24.5 KB
    __shared__ float wst[CHUNK];    // edge weight     24.5 KB
    const int t = threadIdx.x;
    const int base = blockIdx.x * CHUNK;

    for (int i = t; i < NBUCK; i += 1024) h[i] = 0;
    __syncthreads();

    // stage + 512-bucket histogram (bucket = row/98, compiler magic-mul)
    for (int i4 = t; i4 < NI4; i4 += 1024) {
        const int e4 = base + 4 * i4;
        if (e4 + 3 < E) {
            int4   r4 = *(const int4*)(erow + e4);
            int4   c4 = *(const int4*)(ecol + e4);
            float4 w4 = *(const float4*)(ew + e4);
            pkst[4 * i4 + 0] = ((uint)r4.x << 16) | (uint)c4.x;
            pkst[4 * i4 + 1] = ((uint)r4.y << 16) | (uint)c4.y;
            pkst[4 * i4 + 2] = ((uint)r4.z << 16) | (uint)c4.z;
            pkst[4 * i4 + 3] = ((uint)r4.w << 16) | (uint)c4.w;
            *(float4*)(wst + 4 * i4) = w4;
            atomicAdd(&h[(uint)r4.x / BROWS], 1);
            atomicAdd(&h[(uint)r4.y / BROWS], 1);
            atomicAdd(&h[(uint)r4.z / BROWS], 1);
            atomicAdd(&h[(uint)r4.w / BROWS], 1);
        } else {
            for (int k = 0; k < 4; ++k) {
                int e = e4 + k;
                if (e < E) {
                    int row = erow[e];
                    pkst[4 * i4 + k] = ((uint)row << 16) | (uint)ecol[e];
                    wst[4 * i4 + k] = ew[e];
                    atomicAdd(&h[(uint)row / BROWS], 1);
                }
            }
        }
    }
    __syncthreads();

    // claim global base per non-empty bucket
    for (int i = t; i < NBUCK; i += 1024) {
        int c = h[i];
        if (c > 0) h[i] = atomicAdd(&gcnt[i], c);
    }
    __syncthreads();

    const int lim = min(CHUNK, E - base);
    for (int i = t; i < lim; i += 1024) {
        uint  pk = pkst[i];
        float w  = wst[i];
        uint row = pk >> 16;
        uint b   = row / BROWS;                // magic-mul
        uint lr  = row - b * BROWS;            // local row 0..97
        int pos = atomicAdd(&h[b], 1);         // absolute position in bucket
        if (pos < CAPB)
            ecw[(size_t)b * CAPB + pos] =
                make_int2((int)((lr << 16) | (pk & 0xFFFF)), __float_as_int(w));
    }
}

// ---- bucket reduce: LDS sort + register accumulate, 512 blocks (2/CU) ----
__global__ __launch_bounds__(1024) void reduce_kernel(const __half* __restrict__ sup,
                                                      const int* __restrict__ gcnt,
                                                      const int2* __restrict__ ecw,
                                                      const int* __restrict__ active,
                                                      float* __restrict__ out) {
    __shared__ int2 stA[CAPB];   // raw bucket edges      28.7 KB
    __shared__ int2 stB[CAPB];   // row-sorted edges      28.7 KB
    __shared__ int h[128];
    __shared__ int sc[128];
    __shared__ int cur[128];
    const int t = threadIdx.x;
    const int b = blockIdx.x;

    int n = gcnt[b]; if (n > CAPB) n = CAPB;
    const int2* eptr = ecw + (size_t)b * CAPB;

    if (t < 128) h[t] = 0;
    __syncthreads();

    // stage + 98-row histogram (native ds_add_u32)
    for (int i = t; i < n; i += 1024) {
        int2 d = eptr[i];
        stA[i] = d;
        atomicAdd(&h[(d.x >> 16) & 127], 1);
    }
    __syncthreads();

    // 128-entry inclusive scan (entries >= BROWS are zero)
    if (t < 128) sc[t] = h[t];
    __syncthreads();
    for (int off = 1; off < 128; off <<= 1) {
        int u = (t < 128 && t >= off) ? sc[t - off] : 0;
        __syncthreads();
        if (t < 128) sc[t] += u;
        __syncthreads();
    }
    if (t < 128) cur[t] = sc[t] - h[t];
    __syncthreads();

    // scatter to row-sorted order within LDS
    for (int i = t; i < n; i += 1024) {
        int2 d = stA[i];
        int r = (d.x >> 16) & 127;
        int pos = atomicAdd(&cur[r], 1);
        stB[pos] = make_int2(d.x & 0xFFFF, d.y);
    }
    __syncthreads();

    // per-row register reduce: one wave per row, half-wave per edge,
    // each lane gathers a half2 (2 cols) from sup, shfl_xor(32) combine.
    const int wid  = t >> 6;
    const int lane = t & 63;
    const int hl   = lane & 31;
    const bool hi  = lane >= 32;
    const int act  = *active;

    for (int r = wid; r < BROWS; r += 16) {
        int row = b * BROWS + r;
        if (row >= N_NODES) break;   // wave-uniform (tail buckets only)
        const int s = sc[r] - h[r];
        const int e = sc[r];
        float ax = 0.f, ay = 0.f;
        int j = s;
        for (; j + 8 <= e; j += 8) {
#pragma unroll
            for (int q = 0; q < 4; ++q) {
                int2 pa = stB[j + 2 * q];
                int2 pb = stB[j + 2 * q + 1];
                int   col = hi ? pb.x : pa.x;
                float w   = __int_as_float(hi ? pb.y : pa.y);
                const __half2* hp = (const __half2*)(sup + ((size_t)col << 6));
                float2 v = __half22float2(hp[hl]);
                ax += w * v.x;
                ay += w * v.y;
            }
        }
        for (; j + 2 <= e; j += 2) {
            int2 pa = stB[j];
            int2 pb = stB[j + 1];
            int   col = hi ? pb.x : pa.x;
            float w   = __int_as_float(hi ? pb.y : pa.y);
            const __half2* hp = (const __half2*)(sup + ((size_t)col << 6));
            float2 v = __half22float2(hp[hl]);
            ax += w * v.x;
            ay += w * v.y;
        }
        if (j < e) {  // odd tail: hi half contributes zero
            int2 pa = stB[j];
            int   col = pa.x;
            float w   = hi ? 0.f : __int_as_float(pa.y);
            const __half2* hp = (const __half2*)(sup + ((size_t)col << 6));
            float2 v = __half22float2(hp[hl]);
            ax += w * v.x;
            ay += w * v.y;
        }

        ax += __shfl_xor(ax, 32, 64);
        ay += __shfl_xor(ay, 32, 64);

        if (!hi) {
            if (act) { ax = tanhf(ax); ay = tanhf(ay); }
            *(float2*)&out[((size_t)row << 6) + 2 * hl] = make_float2(ax, ay);
        }
    }
}

extern "C" void kernel_launch(void* const* d_in, const int* in_sizes, int n_in,
                              void* d_out, int out_size, void* d_ws, size_t ws_size,
                              hipStream_t stream) {
    const float* feat = (const float*)d_in[0];
    const float* W    = (const float*)d_in[1];
    const int*   erow = (const int*)d_in[2];
    const int*   ecol = (const int*)d_in[3];
    const float* ew   = (const float*)d_in[4];
    const int*   act  = (const int*)d_in[5];
    float* out = (float*)d_out;

    const int E = in_sizes[2];
    const int G = (E + CHUNK - 1) / CHUNK;   // 256 for E = 1.6M

    // workspace carve-up (16B-aligned segments)
    char* ws = (char*)d_ws;
    __half* sup  = (__half*)ws; ws += (size_t)N_NODES * OUT_F * 2;     // 6.4 MB
    int2*   ecw  = (int2*)ws;   ws += (size_t)NBUCK * CAPB * 8;        // 14.7 MB
    int*    gcnt = (int*)ws;    ws += ((size_t)NBUCK * 4 + 15) & ~15;  // 2 KB

    gemm_kernel<<<(N_NODES + 127) / 128, 256, 0, stream>>>(feat, W, sup, gcnt);
    bin_kernel<<<G, 1024, 0, stream>>>(erow, ecol, ew, gcnt, ecw, E);
    reduce_kernel<<<NBUCK, 1024, 0, stream>>>(sup, gcnt, ecw, act, out);
}